// Round 1
// baseline (354.634 us; speedup 1.0000x reference)
//
#include <hip/hip_runtime.h>
#include <cstdint>

#define VOCAB_N 50000
#define EMB_N   16
#define HID_N   32
#define B_N     4096
#define T_N     500

static_assert((T_N & 1) == 0, "T must be even");

__device__ __forceinline__ float frcp(float x) { return __builtin_amdgcn_rcpf(x); }
__device__ __forceinline__ float sigm(float x) {
  // 1/(1+exp(-x)) via v_exp_f32 (exp2) + v_rcp_f32
  return frcp(1.0f + exp2f(x * -1.44269504088896341f));
}
__device__ __forceinline__ float tanh_fast(float x) {
  // tanh(x) = 1 - 2/(exp(2x)+1)
  float e = exp2f(x * 2.88539008177792681f);
  return fmaf(-2.0f, frcp(e + 1.0f), 1.0f);
}

// proj[v][j][g] = bias[g*32+j] + sum_e emb[v][e] * W[e][g*32+j]
__global__ void build_proj_kernel(const float* __restrict__ emb,
                                  const float* __restrict__ W,
                                  const float* __restrict__ bias,
                                  float* __restrict__ proj) {
  __shared__ float Wl[EMB_N * 128];
  __shared__ float bl[128];
  const int tid = threadIdx.x;
  for (int i = tid; i < EMB_N * 128 / 4; i += 256)
    reinterpret_cast<float4*>(Wl)[i] = reinterpret_cast<const float4*>(W)[i];
  if (tid < 32)
    reinterpret_cast<float4*>(bl)[tid] = reinterpret_cast<const float4*>(bias)[tid];
  __syncthreads();

  const int gtid = blockIdx.x * 256 + tid;
  const int v = gtid >> 5;
  const int j = gtid & 31;
  if (v >= VOCAB_N) return;

  const float4* ev = reinterpret_cast<const float4*>(emb + (size_t)v * EMB_N);
  float4 e0 = ev[0], e1 = ev[1], e2 = ev[2], e3 = ev[3];
  const float em[16] = {e0.x,e0.y,e0.z,e0.w, e1.x,e1.y,e1.z,e1.w,
                        e2.x,e2.y,e2.z,e2.w, e3.x,e3.y,e3.z,e3.w};
  float a0 = bl[j], a1 = bl[32+j], a2 = bl[64+j], a3 = bl[96+j];
#pragma unroll
  for (int e = 0; e < 16; ++e) {
    float x = em[e];
    a0 = fmaf(x, Wl[e*128      + j], a0);
    a1 = fmaf(x, Wl[e*128 + 32 + j], a1);
    a2 = fmaf(x, Wl[e*128 + 64 + j], a2);
    a3 = fmaf(x, Wl[e*128 + 96 + j], a3);
  }
  reinterpret_cast<float4*>(proj)[(size_t)v * 32 + j] = make_float4(a0, a1, a2, a3);
}

// One wave = 2 batch rows (32 lanes/row). Lane j of a row owns h[j], c[j] and
// computes z columns {j, 32+j, 64+j, 96+j}. h broadcast via in-wave LDS.
template<bool TABLE>
__global__ __launch_bounds__(256, 2)
void lstm_scan_kernel(const int*   __restrict__ tokens,
                      const float* __restrict__ rec_kernel,  // [32][128]
                      const float* __restrict__ proj,        // [VOCAB][32][4] (TABLE)
                      const float* __restrict__ emb,         // (!TABLE)
                      const float* __restrict__ W,           // (!TABLE)
                      const float* __restrict__ bias,        // (!TABLE)
                      float*       __restrict__ out) {
  __shared__ int   tokl[8][T_N];     // 16000 B
  __shared__ float hbuf[8][HID_N];   // 1024 B

  const int tid  = threadIdx.x;
  const int wv   = tid >> 6;
  const int lane = tid & 63;
  const int half = lane >> 5;
  const int j    = lane & 31;
  const int wrow = wv * 2 + half;               // 0..7
  const int row  = blockIdx.x * 8 + wrow;       // global batch row

  // ---- stage this block's tokens (8 contiguous rows = 4000 ints) ----
  {
    const int4* src = reinterpret_cast<const int4*>(tokens + (size_t)blockIdx.x * 8 * T_N);
    int4* dst = reinterpret_cast<int4*>(&tokl[0][0]);
    for (int i = tid; i < 8 * T_N / 4; i += 256) dst[i] = src[i];
  }

  // ---- recurrent weights into registers: wr[k][g] = R[k][g*32+j] ----
  float wr[HID_N][4];
#pragma unroll
  for (int k = 0; k < HID_N; ++k) {
#pragma unroll
    for (int g = 0; g < 4; ++g) wr[k][g] = rec_kernel[k * 128 + g * 32 + j];
  }

  float wk[EMB_N][4];
  float bb[4];
  if (!TABLE) {
#pragma unroll
    for (int e = 0; e < EMB_N; ++e) {
#pragma unroll
      for (int g = 0; g < 4; ++g) wk[e][g] = W[e * 128 + g * 32 + j];
    }
#pragma unroll
    for (int g = 0; g < 4; ++g) bb[g] = bias[g * 32 + j];
  }
  __syncthreads();

  float c = 0.0f, h = 0.0f;
  float4 h4[8];
#pragma unroll
  for (int q = 0; q < 8; ++q) h4[q] = make_float4(0.f, 0.f, 0.f, 0.f);

  // ---- prologue: prefetch steps 0 and 1 ----
  int tokc  = tokl[wrow][0];
  int tokc1 = tokl[wrow][1];
  float4 pA = make_float4(0,0,0,0), pB = make_float4(0,0,0,0);
  float4 eA[4], eB[4];
  if (TABLE) {
    pA = reinterpret_cast<const float4*>(proj)[(size_t)tokc  * 32 + j];
    pB = reinterpret_cast<const float4*>(proj)[(size_t)tokc1 * 32 + j];
  } else {
#pragma unroll
    for (int q = 0; q < 4; ++q) eA[q] = reinterpret_cast<const float4*>(emb + (size_t)tokc  * EMB_N)[q];
#pragma unroll
    for (int q = 0; q < 4; ++q) eB[q] = reinterpret_cast<const float4*>(emb + (size_t)tokc1 * EMB_N)[q];
  }

  auto body = [&](int t, float4& p, float4* eb) {
    // token for t+2 (prefetch target); latency hidden under the FMA block
    int tp = t + 2; if (tp >= T_N) tp = T_N - 1;
    const int tokp = tokl[wrow][tp];

    float a0, a1, a2, a3;
    if (TABLE) {
      a0 = p.x; a1 = p.y; a2 = p.z; a3 = p.w;
    } else {
      const float em[16] = {eb[0].x,eb[0].y,eb[0].z,eb[0].w, eb[1].x,eb[1].y,eb[1].z,eb[1].w,
                            eb[2].x,eb[2].y,eb[2].z,eb[2].w, eb[3].x,eb[3].y,eb[3].z,eb[3].w};
      a0 = bb[0]; a1 = bb[1]; a2 = bb[2]; a3 = bb[3];
#pragma unroll
      for (int e = 0; e < EMB_N; ++e) {
        float x = em[e];
        a0 = fmaf(x, wk[e][0], a0); a1 = fmaf(x, wk[e][1], a1);
        a2 = fmaf(x, wk[e][2], a2); a3 = fmaf(x, wk[e][3], a3);
      }
    }

    // recurrent matvec: 128 FMAs, 4 independent chains
#pragma unroll
    for (int q = 0; q < 8; ++q) {
      float hx = h4[q].x, hy = h4[q].y, hz = h4[q].z, hw = h4[q].w;
      a0 = fmaf(hx, wr[4*q+0][0], a0); a1 = fmaf(hx, wr[4*q+0][1], a1);
      a2 = fmaf(hx, wr[4*q+0][2], a2); a3 = fmaf(hx, wr[4*q+0][3], a3);
      a0 = fmaf(hy, wr[4*q+1][0], a0); a1 = fmaf(hy, wr[4*q+1][1], a1);
      a2 = fmaf(hy, wr[4*q+1][2], a2); a3 = fmaf(hy, wr[4*q+1][3], a3);
      a0 = fmaf(hz, wr[4*q+2][0], a0); a1 = fmaf(hz, wr[4*q+2][1], a1);
      a2 = fmaf(hz, wr[4*q+2][2], a2); a3 = fmaf(hz, wr[4*q+2][3], a3);
      a0 = fmaf(hw, wr[4*q+3][0], a0); a1 = fmaf(hw, wr[4*q+3][1], a1);
      a2 = fmaf(hw, wr[4*q+3][2], a2); a3 = fmaf(hw, wr[4*q+3][3], a3);
    }

    // issue prefetch for step t+2 (consumed two bodies later)
    if (TABLE) {
      p = reinterpret_cast<const float4*>(proj)[(size_t)tokp * 32 + j];
    } else {
#pragma unroll
      for (int q = 0; q < 4; ++q)
        eb[q] = reinterpret_cast<const float4*>(emb + (size_t)tokp * EMB_N)[q];
    }

    // gates + state update
    float ig = sigm(a0);
    float fg = sigm(a1);
    float gg = tanh_fast(a2);
    float og = sigm(a3);
    float cn = fmaf(fg, c, ig * gg);
    float hn = og * tanh_fast(cn);
    if (tokc != 0) { h = hn; c = cn; }   // per-lane cndmask (mask = token!=0)

    // in-wave h broadcast: write own element, read full row (DS pipe is
    // in-order per wave; both halves of the wave are distinct rows)
    hbuf[wrow][j] = h;
    asm volatile("" ::: "memory");
#pragma unroll
    for (int q = 0; q < 8; ++q)
      h4[q] = reinterpret_cast<const float4*>(&hbuf[wrow][0])[q];
    asm volatile("" ::: "memory");

    // rotate token pipeline
    tokc = tokc1;
    tokc1 = tokp;
  };

  for (int t = 0; t < T_N; t += 2) {
    body(t,     pA, eA);
    body(t + 1, pB, eB);
  }

  out[(size_t)row * HID_N + j] = h;
}

extern "C" void kernel_launch(void* const* d_in, const int* in_sizes, int n_in,
                              void* d_out, int out_size, void* d_ws, size_t ws_size,
                              hipStream_t stream) {
  const int*   tokens = (const int*)  d_in[0];
  const float* emb    = (const float*)d_in[1];
  const float* W      = (const float*)d_in[2];
  const float* rec    = (const float*)d_in[3];
  const float* bias   = (const float*)d_in[4];
  float* out = (float*)d_out;

  const size_t need = (size_t)VOCAB_N * 32 * 4 * sizeof(float);  // 25.6 MB
  if (ws_size >= need) {
    float* proj = (float*)d_ws;
    build_proj_kernel<<<(VOCAB_N * 32) / 256, 256, 0, stream>>>(emb, W, bias, proj);
    lstm_scan_kernel<true><<<B_N / 8, 256, 0, stream>>>(tokens, rec, proj,
                                                        emb, W, bias, out);
  } else {
    lstm_scan_kernel<false><<<B_N / 8, 256, 0, stream>>>(tokens, rec, nullptr,
                                                         emb, W, bias, out);
  }
}